// Round 5
// baseline (149.995 us; speedup 1.0000x reference)
//
#include <hip/hip_runtime.h>
#include <stdint.h>

// SymmetryControl: B=16, C=96, H=96, W=96 fp32.
// out[b,c,h,i] = num/den, 6 taps of the same 96-wide row (3 shifts + 2 flips),
// gated by sigmoid(s[b,0..4]).
//
// R5: R2-R4 were all latency-bound (~50 us) on the global->VGPR->use chain
// (VGPR_Count 16-32 -> tiny load window). Replace staging with async
// global_load_lds width=16: block (24,16) makes lane i's LDS target byte 16*i
// (the required wave-uniform-base + lane*16 pattern; LDS rows UNPADDED 96
// floats). Phase 2 is fully vectorized: 12 ds_read_b128 taps + float4 store
// (wave writes 1 KB contiguous).

#define WDIM 96
#define QDIM 24          // float4 segments per row
#define ROWS 16          // rows per block (RPB % ROWS == 0)
#define RPB  9216        // rows per batch (C*H)

typedef float f4 __attribute__((ext_vector_type(4)));

__global__ __launch_bounds__(QDIM * ROWS)
void symctl_kernel(const float* __restrict__ x,
                   const float* __restrict__ s,
                   const float* __restrict__ w,
                   float* __restrict__ out) {
    __shared__ float lx[ROWS * WDIM];   // raw x block, linear layout
    __shared__ float lw[ROWS * WDIM];   // raw w block, linear layout

    const int t       = threadIdx.x;              // 0..23 float4 segment
    const int ry      = threadIdx.y;              // 0..15 row in block
    const int rowbase = blockIdx.x * ROWS;        // block-uniform
    const int row     = rowbase + ry;
    const int b       = rowbase / RPB;            // uniform batch index

    const int flat = ry * QDIM + t;               // 0..383; lane i of wave -> lds byte 16*i

    // ---- phase 1: async DMA global -> LDS, no VGPR round trip ----
    const float* gx = x + (size_t)rowbase * WDIM + 4 * (size_t)flat;
    const float* gw = w + (size_t)rowbase * WDIM + 4 * (size_t)flat;
    __builtin_amdgcn_global_load_lds(
        (const __attribute__((address_space(1))) uint32_t*)gx,
        (__attribute__((address_space(3))) uint32_t*)(lx + 4 * flat),
        16, 0, 0);
    __builtin_amdgcn_global_load_lds(
        (const __attribute__((address_space(1))) uint32_t*)gw,
        (__attribute__((address_space(3))) uint32_t*)(lw + 4 * flat),
        16, 0, 0);

    // sigmoid gates while the DMA flies (s address wave-uniform -> s_load)
    const float* sbp = s + b * 5;
    const float sg0 = 1.0f / (1.0f + __expf(-sbp[0]));
    const float sg1 = 1.0f / (1.0f + __expf(-sbp[1]));
    const float sg2 = 1.0f / (1.0f + __expf(-sbp[2]));
    const float sg3 = 1.0f / (1.0f + __expf(-sbp[3]));
    const float sg4 = 1.0f / (1.0f + __expf(-sbp[4]));

    __syncthreads();   // drains vmcnt (global_load_lds) + barrier

    // ---- phase 2: vector tap gather from LDS ----
    // tap bases in float4 units, mod 24 (flip taps component-reversed)
    int qa = t - 6;  if (qa < 0) qa += QDIM;        // i-24
    int qb = t - 12; if (qb < 0) qb += QDIM;        // i-48
    int qc = t + 6;  if (qc >= QDIM) qc -= QDIM;    // i-72
    int qd = 5  - t; if (qd < 0) qd += QDIM;        // flip base (20-4t)/4
    int qe = 11 - t; if (qe < 0) qe += QDIM;        // flip base (44-4t)/4

    const f4* __restrict__ xrow = (const f4*)(lx + ry * WDIM);
    const f4* __restrict__ wrow = (const f4*)(lw + ry * WDIM);

    const f4 X0 = xrow[t],  W0 = wrow[t];
    const f4 Xa = xrow[qa], Wa = wrow[qa];
    const f4 Xb = xrow[qb], Wb = wrow[qb];
    const f4 Xc = xrow[qc], Wc = wrow[qc];
    const f4 Xd = xrow[qd], Wd = wrow[qd];
    const f4 Xe = xrow[qe], We = wrow[qe];

    const float* x0p = (const float*)&X0; const float* w0p = (const float*)&W0;
    const float* xap = (const float*)&Xa; const float* wap = (const float*)&Wa;
    const float* xbp = (const float*)&Xb; const float* wbp = (const float*)&Wb;
    const float* xcp = (const float*)&Xc; const float* wcp = (const float*)&Wc;
    const float* xdp = (const float*)&Xd; const float* wdp = (const float*)&Wd;
    const float* xep = (const float*)&Xe; const float* wep = (const float*)&We;

    f4 res;
    float* rp = (float*)&res;
#pragma unroll
    for (int j = 0; j < 4; ++j) {
        const int r = 3 - j;  // flip taps are component-reversed
        const float w0 = w0p[j];
        const float ga = sg0 * wap[j], gb = sg1 * wbp[j], gc = sg2 * wcp[j];
        const float gd = sg3 * wdp[r], ge = sg4 * wep[r];

        float num = w0 * x0p[j];
        num = fmaf(ga, xap[j], num);
        num = fmaf(gb, xbp[j], num);
        num = fmaf(gc, xcp[j], num);
        num = fmaf(gd, xdp[r], num);
        num = fmaf(ge, xep[r], num);

        const float den = w0 + ga + gb + gc + gd + ge;
        rp[j] = num * __builtin_amdgcn_rcpf(den);
    }

    ((f4*)(out + (size_t)row * WDIM))[t] = res;   // wave store = 1 KB contiguous
}

extern "C" void kernel_launch(void* const* d_in, const int* in_sizes, int n_in,
                              void* d_out, int out_size, void* d_ws, size_t ws_size,
                              hipStream_t stream) {
    const float* x = (const float*)d_in[0];
    const float* s = (const float*)d_in[1];
    const float* w = (const float*)d_in[2];
    float* out = (float*)d_out;

    const int n_rows = in_sizes[0] / WDIM;   // 147456
    const int grid = n_rows / ROWS;          // 9216

    dim3 block(QDIM, ROWS);
    symctl_kernel<<<grid, block, 0, stream>>>(x, s, w, out);
}